// Round 24
// baseline (1338.982 us; speedup 1.0000x reference)
//
#include <hip/hip_runtime.h>

#define BB 64
#define TT 256
#define DD 512
#define HH 1024
#define NCLS 1000

#define NB   256       // persistent blocks (1/CU via LDS)
#define L0B  128       // blocks [0,128): layer0; [128,256): layer1
#define COLS 8         // h-columns per block
#define RING 64        // h ring depth (cross-layer slack; stale-line guard)
#define HSZ  (BB * HH) // elements per packed h snapshot ([4][32][64][8] f16)
#define CHK0 48
#define CHK1 64
#define TS0  (CHK0 * 512)
#define TS1  (CHK1 * 512)
#define GRP  32        // epoch replica lines
#define EPSLP 4
// LDS: packed W frags (2 tiles) + padded khalf partial buf + h-bounce buf
#define DYNLDS (2 * TS1 * 2 + 4 * 64 * 9 * 4 + 64 * 8 * 2)  // 141312 B
#define BARWORDS ((2 * L0B + 2 * GRP) * 32)

typedef _Float16 f16;
typedef _Float16 f16x8 __attribute__((ext_vector_type(8)));
typedef float f32x4 __attribute__((ext_vector_type(4)));
typedef int i32x4 __attribute__((ext_vector_type(4)));

#define MFMA16(af, bf, acc) __builtin_amdgcn_mfma_f32_16x16x32_f16((af), (bf), (acc), 0, 0, 0)
#define FSIG(x) (1.f / (1.f + __expf(-(x))))
#define FTANH(x) (1.f - 2.f / (__expf(2.f * (x)) + 1.f))
#define ALOAD __HIP_MEMORY_SCOPE_AGENT

// ---- asm-forced deep load pipeline, packed layout (chunk stride 1024B) ----
template <int N, int I = 0>
__device__ __forceinline__ void glP(i32x4* A, const f16* base) {
  if constexpr (I < N) {
    asm volatile("global_load_dwordx4 %0, %1, off offset:%2"
                 : "=v"(A[I]) : "v"(base + (I >> 2) * 2048), "n"((I & 3) * 1024));
    glP<N, I + 1>(A, base);
  }
}
// consume TOTAL chunks (groups of 8, progressive counted vmcnt); B from LDS.
template <int TOTAL, int EXTRA, int BBASE, int G = 0>
__device__ __forceinline__ void mf2(i32x4* A, const f16* w0, const f16* w1,
                                    f32x4& a0, f32x4& a1, f32x4& b0, f32x4& b1) {
  if constexpr (G * 8 < TOTAL) {
    asm volatile("s_waitcnt vmcnt(%0)" :: "n"(TOTAL - (G + 1) * 8 + EXTRA)
                 : "memory");
    __builtin_amdgcn_sched_barrier(0);
    #pragma unroll
    for (int k = 0; k < 8; ++k) {
      int ck = G * 8 + k;
      f16x8 a;
      __builtin_memcpy(&a, &A[ck], 16);
      const f16* p0 = w0 + (size_t)(BBASE + ck) * 512;
      const f16* p1 = w1 + (size_t)(BBASE + ck) * 512;
      if (ck & 1) {
        a1 = MFMA16(a, *(const f16x8*)p0, a1);
        b1 = MFMA16(a, *(const f16x8*)p1, b1);
      } else {
        a0 = MFMA16(a, *(const f16x8*)p0, a0);
        b0 = MFMA16(a, *(const f16x8*)p1, b0);
      }
    }
    mf2<TOTAL, EXTRA, BBASE, G + 1>(A, w0, w1, a0, a1, b0, b1);
  }
}
// consume TOTAL chunks: tile0 B from REGISTERS (opaque-pinned, cannot be
// rematerialized from LDS), tile1 B from LDS.
template <int TOTAL, int EXTRA, int BBASE, int G = 0>
__device__ __forceinline__ void mfR1(i32x4* A, const f16x8* wb0, const f16* w1,
                                     f32x4& a0, f32x4& a1, f32x4& b0, f32x4& b1) {
  if constexpr (G * 8 < TOTAL) {
    asm volatile("s_waitcnt vmcnt(%0)" :: "n"(TOTAL - (G + 1) * 8 + EXTRA)
                 : "memory");
    __builtin_amdgcn_sched_barrier(0);
    #pragma unroll
    for (int k = 0; k < 8; ++k) {
      int ck = G * 8 + k;
      f16x8 a;
      __builtin_memcpy(&a, &A[ck], 16);
      const f16* p1 = w1 + (size_t)(BBASE + ck) * 512;
      if (ck & 1) {
        a1 = MFMA16(a, wb0[ck], a1);
        b1 = MFMA16(a, *(const f16x8*)p1, b1);
      } else {
        a0 = MFMA16(a, wb0[ck], a0);
        b0 = MFMA16(a, *(const f16x8*)p1, b0);
      }
    }
    mfR1<TOTAL, EXTRA, BBASE, G + 1>(A, wb0, w1, a0, a1, b0, b1);
  }
}

// ---- prep: x [B][T][D] fp32 -> packed xpk [T][4][16][64][8] fp16 ----
__global__ __launch_bounds__(256) void prep_x_kernel(const float* __restrict__ x,
                                                     f16* __restrict__ xpk) {
  int idx = blockIdx.x * 256 + threadIdx.x;  // over T*B*(D/8)
  int seg = idx & 63;
  int b   = (idx >> 6) & 63;
  int t   = idx >> 12;
  float4 u = *(const float4*)(x + ((size_t)b * TT + t) * DD + seg * 8);
  float4 v = *(const float4*)(x + ((size_t)b * TT + t) * DD + seg * 8 + 4);
  f16x8 o = {(f16)u.x, (f16)u.y, (f16)u.z, (f16)u.w,
             (f16)v.x, (f16)v.y, (f16)v.z, (f16)v.w};
  int ch = seg >> 2, kgrp = seg & 3;
  *(f16x8*)(xpk + ((size_t)((t * 4 + (b >> 4)) * 16 + ch) * 64 +
                   kgrp * 16 + (b & 15)) * 8) = o;
}

// ---- persistent 2-layer LSTM: R23 + opacity-pinned tile0 B-residency ----
// R24 = R23 with ONE fix: wb0 values are opacity-pinned via empty asm
// ("+v") after preload. R23's VGPR=128 showed the allocator REMATERIALIZED
// wb0 from LDS inside the loop (values traceable to LDS loads), silently
// restoring the ds_reads. Asm-defined values cannot be rematerialized:
// the allocator must keep them resident (budget 256 via launch_bounds(512,1))
// or visibly spill (WRITE_SIZE tells). Everything else R23-verbatim.
__global__ __launch_bounds__(512, 1) void lstm_persistent(
    const f16* __restrict__ xpk,
    const float* __restrict__ Wih0, const float* __restrict__ Whh0,
    const float* __restrict__ bih0, const float* __restrict__ bhh0,
    const float* __restrict__ Wih1, const float* __restrict__ Whh1,
    const float* __restrict__ bih1, const float* __restrict__ bhh1,
    f16* __restrict__ h0ring, f16* __restrict__ h1ring, int* __restrict__ bar) {
  extern __shared__ f16 lds[];
  const int bid  = blockIdx.x;
  const bool IS1 = (bid >= L0B);
  const int j0   = (IS1 ? bid - L0B : bid) * COLS;
  const int tid  = threadIdx.x;
  const int wv   = tid >> 6;
  const int lane = tid & 63;
  const int kh   = wv >> 2;     // K-half
  const int bt   = wv & 3;      // batch tile (16 rows)
  const int col  = lane & 15;
  const int kgrp = lane >> 4;
  const int jc   = col & 7;
  const int ch0  = j0 >> 5;
  const int kg0  = (j0 >> 3) & 3;

  const int CHK = IS1 ? CHK1 : CHK0;
  const int TS  = IS1 ? TS1 : TS0;
  const int DIN = IS1 ? HH : DD;
  f16* Wpk    = lds;
  float* pbuf = (float*)(lds + 2 * TS1);     // [4][64] stride 9 (conflict-free)
  f16* hbuf   = (f16*)(pbuf + 4 * 64 * 9);   // [64][8]

  // ---- prologue: pack weights into MFMA-fragment order (fp32 -> fp16) ----
  {
    const float* Wi = IS1 ? Wih1 : Wih0;
    const float* Wh = IS1 ? Whh1 : Whh0;
    const int grow = (kh * 2 + (col >> 3)) * HH + j0 + jc;
    const float* rowi = Wi + (size_t)grow * DIN;
    const float* rowh = Wh + (size_t)grow * HH;
    for (int ck = bt; ck < CHK; ck += 4) {
      int k = ck * 32 + kgrp * 8;
      const float* src = (k < DIN) ? (rowi + k) : (rowh + (k - DIN));
      float4 u = *(const float4*)src;
      float4 v = *(const float4*)(src + 4);
      f16x8 w = {(f16)u.x, (f16)u.y, (f16)u.z, (f16)u.w,
                 (f16)v.x, (f16)v.y, (f16)v.z, (f16)v.w};
      *(f16x8*)(Wpk + (size_t)kh * TS + (size_t)ck * 512 + lane * 8) = w;
    }
  }
  const float* bi = IS1 ? bih1 : bih0;
  const float* bh = IS1 ? bhh1 : bhh0;
  const int g0 = (col < 8) ? 0 : 1;
  const int g1 = (col < 8) ? 2 : 3;
  const float bias0 = bi[g0 * HH + j0 + jc] + bh[g0 * HH + j0 + jc];
  const float bias1 = bi[g1 * HH + j0 + jc] + bh[g1 * HH + j0 + jc];
  __syncthreads();

  const f16* w0 = Wpk + lane * 8;
  const f16* w1 = Wpk + (size_t)TS + lane * 8;

  // ---- tile0 critical B-fragments -> registers, opacity-pinned ----
  f16x8 wb0[16];
  {
    const int cbase = (IS1 ? 32 : 16) + kh * 16;
    #pragma unroll
    for (int ck = 0; ck < 16; ++ck)
      wb0[ck] = *(const f16x8*)(w0 + (size_t)(cbase + ck) * 512);
    #pragma unroll
    for (int ck = 0; ck < 16; ++ck)
      asm volatile("" : "+v"(wb0[ck]));   // opaque: no remat from LDS
  }

  float creg[4] = {0.f, 0.f, 0.f, 0.f};
  int* flag0 = bar;
  int* flag1 = bar + L0B * 32;
  int* ep0   = bar + 2 * L0B * 32;
  int* ep1   = ep0 + GRP * 32;
  const int myrep = (IS1 ? bid - L0B : bid) & (GRP - 1);

  auto cellstore = [&](f32x4 aA0, f32x4 aA1, f32x4 aB0, f32x4 aB1, f16* hw) {
    if (kh == 1) {
      #pragma unroll
      for (int r = 0; r < 4; ++r) {
        pbuf[((size_t)bt * 64 + lane) * 9 + r]     = aA0[r] + aA1[r];
        pbuf[((size_t)bt * 64 + lane) * 9 + 4 + r] = aB0[r] + aB1[r];
      }
    }
    __syncthreads();
    if (kh == 0) {
      #pragma unroll
      for (int r = 0; r < 4; ++r) {
        float pv0 = aA0[r] + aA1[r] + pbuf[((size_t)bt * 64 + lane) * 9 + r] + bias0;
        float pv1 = aB0[r] + aB1[r] + pbuf[((size_t)bt * 64 + lane) * 9 + 4 + r] + bias1;
        float q0 = __shfl_xor(pv0, 8);
        float q1 = __shfl_xor(pv1, 8);
        if (col < 8) {
          float ig = FSIG(pv0);
          float fg = FSIG(q0);
          float gg = FTANH(pv1);
          float og = FSIG(q1);
          float cc = fg * creg[r] + ig * gg;
          creg[r] = cc;
          hbuf[((size_t)bt * 16 + kgrp * 4 + r) * 8 + jc] = (f16)(og * FTANH(cc));
        }
      }
      if (lane < 16) {
        f16x8 hv = *(const f16x8*)(hbuf + ((size_t)bt * 16 + lane) * 8);
        f16* dst = hw + ((size_t)(bt * 32 + ch0) * 64 + kg0 * 16 + lane) * 8;
        i32x4 hvi;
        __builtin_memcpy(&hvi, &hv, 16);
        asm volatile("global_store_dwordx4 %0, %1, off sc1"
                     :: "v"(dst), "v"(hvi) : "memory");
      }
    }
  };

  if (!IS1) {
    // ================= layer 0 (R20 structure) =================
    const bool AGG = (bid == 0);
    i32x4 afs[8];   // x slack: 8 chunks per kh half (prefetched)
    i32x4 afc[16];  // critical h0 half
    glP<8>(afs, xpk + (size_t)(0 * 4 + bt) * 16 * 512 +
                (size_t)kh * 8 * 512 + lane * 8);
    for (int t = 0; t < TT; ++t) {
      f32x4 aA0 = {0.f,0.f,0.f,0.f}, aA1 = {0.f,0.f,0.f,0.f};
      f32x4 aB0 = {0.f,0.f,0.f,0.f}, aB1 = {0.f,0.f,0.f,0.f};
      if (AGG) {
        if (tid < L0B)
          while (__hip_atomic_load(flag0 + tid * 32, __ATOMIC_RELAXED, ALOAD) < t)
            __builtin_amdgcn_s_sleep(1);
        if (tid == 256) {
          while (__hip_atomic_load(ep1 + myrep * 32, __ATOMIC_RELAXED, ALOAD) < t - (RING - 1))
            __builtin_amdgcn_s_sleep(EPSLP);
        }
        __syncthreads();
        if (tid < GRP)
          __hip_atomic_store(ep0 + tid * 32, t, __ATOMIC_RELAXED, ALOAD);
        if (kh == 0) mf2<8, 0, 0>(afs, w0, w1, aA0, aA1, aB0, aB1);
        else         mf2<8, 0, 8>(afs, w0, w1, aA0, aA1, aB0, aB1);
      } else {
        if (kh == 0) mf2<8, 0, 0>(afs, w0, w1, aA0, aA1, aB0, aB1);
        else         mf2<8, 0, 8>(afs, w0, w1, aA0, aA1, aB0, aB1);
        if (tid == 0) {
          while (__hip_atomic_load(ep0 + myrep * 32, __ATOMIC_RELAXED, ALOAD) < t)
            __builtin_amdgcn_s_sleep(EPSLP);
        }
        if (tid == 256) {
          while (__hip_atomic_load(ep1 + myrep * 32, __ATOMIC_RELAXED, ALOAD) < t - (RING - 1))
            __builtin_amdgcn_s_sleep(EPSLP);
        }
        __syncthreads();
      }
      // --- critical: h0[t-1], 16 chunks/wave; B0 registers, B1 LDS ---
      const f16* hp = h0ring + (size_t)((t - 1) & (RING - 1)) * HSZ +
                      (size_t)(bt * 32 + kh * 16) * 512 + lane * 8;
      glP<16>(afc, hp);
      if (kh == 0) mfR1<16, 0, 16>(afc, wb0, w1, aA0, aA1, aB0, aB1);
      else         mfR1<16, 0, 32>(afc, wb0, w1, aA0, aA1, aB0, aB1);
      cellstore(aA0, aA1, aB0, aB1, h0ring + (size_t)(t & (RING - 1)) * HSZ);
      asm volatile("s_waitcnt vmcnt(0)" ::: "memory");
      __syncthreads();
      if (tid == 0)
        __hip_atomic_store(flag0 + bid * 32, t + 1, __ATOMIC_RELAXED, ALOAD);
      if (t + 1 < TT)
        glP<8>(afs, xpk + (size_t)((t + 1) * 4 + bt) * 16 * 512 +
                    (size_t)kh * 8 * 512 + lane * 8);
    }
    if (AGG) {
      if (tid < L0B)
        while (__hip_atomic_load(flag0 + tid * 32, __ATOMIC_RELAXED, ALOAD) < TT)
          __builtin_amdgcn_s_sleep(1);
      __syncthreads();
      if (tid < GRP)
        __hip_atomic_store(ep0 + tid * 32, TT, __ATOMIC_RELAXED, ALOAD);
    }
  } else {
    // ================= layer 1 (R20 structure) =================
    const bool AGG = (bid == L0B);
    i32x4 afs[16];  // h0 slack: 16 chunks per kh half (prefetched)
    i32x4 afc[16];  // critical h1 half
    {  // prologue: gate h0[0] ready, then slack loads in flight (both kh)
      if (tid == 0)
        while (__hip_atomic_load(ep0 + myrep * 32, __ATOMIC_RELAXED, ALOAD) < 1)
          __builtin_amdgcn_s_sleep(EPSLP);
      __syncthreads();
      glP<16>(afs, h0ring + (size_t)0 * HSZ +
                   (size_t)(bt * 32 + kh * 16) * 512 + lane * 8);
    }
    for (int u = 0; u < TT; ++u) {
      f32x4 aA0 = {0.f,0.f,0.f,0.f}, aA1 = {0.f,0.f,0.f,0.f};
      f32x4 aB0 = {0.f,0.f,0.f,0.f}, aB1 = {0.f,0.f,0.f,0.f};
      if (AGG) {
        // --- agg: poll + publish FIRST, slack after (off critical chain) ---
        if (tid < L0B)
          while (__hip_atomic_load(flag1 + tid * 32, __ATOMIC_RELAXED, ALOAD) < u)
            __builtin_amdgcn_s_sleep(1);
        __syncthreads();
        if (tid < GRP)
          __hip_atomic_store(ep1 + tid * 32, u, __ATOMIC_RELAXED, ALOAD);
        if (kh == 0) mf2<16, 0, 0>(afs, w0, w1, aA0, aA1, aB0, aB1);
        else         mf2<16, 0, 16>(afs, w0, w1, aA0, aA1, aB0, aB1);
      } else {
        // --- non-agg: slack consume overlaps the epoch wait ---
        if (kh == 0) mf2<16, 0, 0>(afs, w0, w1, aA0, aA1, aB0, aB1);
        else         mf2<16, 0, 16>(afs, w0, w1, aA0, aA1, aB0, aB1);
        if (tid == 0) {
          while (__hip_atomic_load(ep1 + myrep * 32, __ATOMIC_RELAXED, ALOAD) < u)
            __builtin_amdgcn_s_sleep(EPSLP);
        }
        __syncthreads();
      }
      // --- critical: h1[u-1], 16 chunks/wave; B0 registers, B1 LDS ---
      const f16* h1p = h1ring + (size_t)((u - 1) & (RING - 1)) * HSZ +
                       (size_t)(bt * 32 + kh * 16) * 512 + lane * 8;
      glP<16>(afc, h1p);
      if (kh == 0) mfR1<16, 0, 32>(afc, wb0, w1, aA0, aA1, aB0, aB1);
      else         mfR1<16, 0, 48>(afc, wb0, w1, aA0, aA1, aB0, aB1);
      cellstore(aA0, aA1, aB0, aB1, h1ring + (size_t)(u & (RING - 1)) * HSZ);
      asm volatile("s_waitcnt vmcnt(0)" ::: "memory");
      __syncthreads();
      if (tid == 0)
        __hip_atomic_store(flag1 + (bid - L0B) * 32, u + 1, __ATOMIC_RELAXED, ALOAD);
      // --- gated slack prefetch h0[u+1] (both kh halves) ---
      if (u + 1 < TT) {
        if (tid == 256)
          while (__hip_atomic_load(ep0 + myrep * 32, __ATOMIC_RELAXED, ALOAD) < u + 2)
            __builtin_amdgcn_s_sleep(EPSLP);
        __syncthreads();
        glP<16>(afs, h0ring + (size_t)((u + 1) & (RING - 1)) * HSZ +
                     (size_t)(bt * 32 + kh * 16) * 512 + lane * 8);
      }
    }
  }
}

// ---- FC over packed finals ----
__global__ __launch_bounds__(256) void fc_kernel(const f16* __restrict__ h0f,
                                                 const f16* __restrict__ h1f,
                                                 const float* __restrict__ Wfc,
                                                 const float* __restrict__ bfc,
                                                 float* __restrict__ out) {
  __shared__ f16 hl[64][264];
  __shared__ float Wl[4][260];
  const int tid = threadIdx.x;
  const int cl0 = blockIdx.x * 4;
  const int b   = tid >> 2;
  const int cq  = tid & 3;
  float a = 0.f;
  for (int k0 = 0; k0 < 2 * HH; k0 += 256) {
    #pragma unroll
    for (int i = 0; i < 8; i++) {
      int v   = tid + i * 256;
      int row = v >> 5;
      int kk  = (v & 31) * 8;
      int kg  = k0 + kk;
      int kg2 = (kg < HH) ? kg : kg - HH;
      const f16* bse = (kg < HH) ? h0f : h1f;
      const f16* src = bse + ((size_t)((row >> 4) * 32 + (kg2 >> 5)) * 64 +
                              ((kg2 >> 3) & 3) * 16 + (row & 15)) * 8;
      *(f16x8*)(&hl[row][kk]) = *(const f16x8*)src;
    }
    {
      int row = tid >> 6;
      int kk  = (tid & 63) * 4;
      *(float4*)(&Wl[row][kk]) = *(const float4*)(Wfc + (size_t)(cl0 + row) * (2 * HH) + k0 + kk);
    }
    __syncthreads();
    #pragma unroll 8
    for (int k = 0; k < 256; k++) a += (float)hl[b][k] * Wl[cq][k];
    __syncthreads();
  }
  out[(size_t)b * NCLS + cl0 + cq] = a + bfc[cl0 + cq];
}

extern "C" void kernel_launch(void* const* d_in, const int* in_sizes, int n_in,
                              void* d_out, int out_size, void* d_ws, size_t ws_size,
                              hipStream_t stream) {
  const float* x    = (const float*)d_in[0];
  const float* Wih0 = (const float*)d_in[1];
  const float* Whh0 = (const float*)d_in[2];
  const float* bih0 = (const float*)d_in[3];
  const float* bhh0 = (const float*)d_in[4];
  const float* Wih1 = (const float*)d_in[5];
  const float* Whh1 = (const float*)d_in[6];
  const float* bih1 = (const float*)d_in[7];
  const float* bhh1 = (const float*)d_in[8];
  const float* Wfc  = (const float*)d_in[9];
  const float* bfc  = (const float*)d_in[10];
  float* out = (float*)d_out;

  char* p = (char*)d_ws;
  auto alloc = [&](size_t bytes) {
    char* r = p;
    p += (bytes + 255) & ~(size_t)255;
    return r;
  };
  f16* xpk    = (f16*)alloc((size_t)BB * TT * DD * 2);
  f16* h0ring = (f16*)alloc((size_t)RING * HSZ * 2);
  f16* h1ring = (f16*)alloc((size_t)RING * HSZ * 2);
  int* bar    = (int*)alloc((size_t)BARWORDS * 4);

  if ((size_t)(p - (char*)d_ws) > ws_size) return;  // ws too small: bail cleanly

  (void)hipMemsetAsync(bar, 0, (size_t)BARWORDS * 4, stream);
  // slot RING-1 = t=-1 zeros for both rings
  (void)hipMemsetAsync(h0ring + (size_t)(RING - 1) * HSZ, 0, (size_t)HSZ * 2, stream);
  (void)hipMemsetAsync(h1ring + (size_t)(RING - 1) * HSZ, 0, (size_t)HSZ * 2, stream);

  prep_x_kernel<<<dim3(TT * BB * (DD / 8) / 256), dim3(256), 0, stream>>>(x, xpk);

  (void)hipFuncSetAttribute((const void*)lstm_persistent,
                            hipFuncAttributeMaxDynamicSharedMemorySize, DYNLDS);
  lstm_persistent<<<dim3(NB), dim3(512), DYNLDS, stream>>>(
      xpk, Wih0, Whh0, bih0, bhh0, Wih1, Whh1, bih1, bhh1, h0ring, h1ring, bar);

  // h0[255] -> slot 255&63 = 63; h1[255] -> slot 63
  fc_kernel<<<dim3(NCLS / 4), dim3(256), 0, stream>>>(
      h0ring + (size_t)(RING - 1) * HSZ, h1ring + (size_t)(RING - 1) * HSZ,
      Wfc, bfc, out);
}

// Round 25
// 1288.793 us; speedup vs baseline: 1.0389x; 1.0389x over previous
//
#include <hip/hip_runtime.h>

#define BB 64
#define TT 256
#define DD 512
#define HH 1024
#define NCLS 1000

#define NB   256       // persistent blocks (1/CU via LDS)
#define L0B  128       // blocks [0,128): layer0; [128,256): layer1
#define COLS 8         // h-columns per block
#define RING 64        // h ring depth (cross-layer slack; stale-line guard)
#define HSZ  (BB * HH) // elements per packed h snapshot ([4][32][64][8] f16)
#define CHK0 48
#define CHK1 64
#define TS0  (CHK0 * 512)
#define TS1  (CHK1 * 512)
#define GRP  32        // epoch replica lines
#define EPSLP 4
// LDS: packed W frags (2 tiles) + padded khalf partial buf + h-bounce buf
#define DYNLDS (2 * TS1 * 2 + 4 * 64 * 9 * 4 + 64 * 8 * 2)  // 141312 B
#define BARWORDS ((2 * L0B + 2 * GRP) * 32)

typedef _Float16 f16;
typedef _Float16 f16x8 __attribute__((ext_vector_type(8)));
typedef float f32x4 __attribute__((ext_vector_type(4)));
typedef int i32x4 __attribute__((ext_vector_type(4)));

#define MFMA16(af, bf, acc) __builtin_amdgcn_mfma_f32_16x16x32_f16((af), (bf), (acc), 0, 0, 0)
#define FSIG(x) (1.f / (1.f + __expf(-(x))))
#define FTANH(x) (1.f - 2.f / (__expf(2.f * (x)) + 1.f))
#define ALOAD __HIP_MEMORY_SCOPE_AGENT

// ---- asm-forced deep load pipeline, packed layout (chunk stride 1024B) ----
template <int N, int I = 0>
__device__ __forceinline__ void glP(i32x4* A, const f16* base) {
  if constexpr (I < N) {
    asm volatile("global_load_dwordx4 %0, %1, off offset:%2"
                 : "=v"(A[I]) : "v"(base + (I >> 2) * 2048), "n"((I & 3) * 1024));
    glP<N, I + 1>(A, base);
  }
}
// consume TOTAL chunks (groups of 8, progressive counted vmcnt); each chunk
// feeds BOTH weight tiles; acc split by ck parity. EXTRA = vmem ops issued
// AFTER this stream (or still outstanding beyond it) per FIFO vmcnt.
template <int TOTAL, int EXTRA, int BBASE, int G = 0>
__device__ __forceinline__ void mf2(i32x4* A, const f16* w0, const f16* w1,
                                    f32x4& a0, f32x4& a1, f32x4& b0, f32x4& b1) {
  if constexpr (G * 8 < TOTAL) {
    asm volatile("s_waitcnt vmcnt(%0)" :: "n"(TOTAL - (G + 1) * 8 + EXTRA)
                 : "memory");
    __builtin_amdgcn_sched_barrier(0);
    #pragma unroll
    for (int k = 0; k < 8; ++k) {
      int ck = G * 8 + k;
      f16x8 a;
      __builtin_memcpy(&a, &A[ck], 16);
      const f16* p0 = w0 + (size_t)(BBASE + ck) * 512;
      const f16* p1 = w1 + (size_t)(BBASE + ck) * 512;
      if (ck & 1) {
        a1 = MFMA16(a, *(const f16x8*)p0, a1);
        b1 = MFMA16(a, *(const f16x8*)p1, b1);
      } else {
        a0 = MFMA16(a, *(const f16x8*)p0, a0);
        b0 = MFMA16(a, *(const f16x8*)p1, b0);
      }
    }
    mf2<TOTAL, EXTRA, BBASE, G + 1>(A, w0, w1, a0, a1, b0, b1);
  }
}

// ---- prep: x [B][T][D] fp32 -> packed xpk [T][4][16][64][8] fp16 ----
__global__ __launch_bounds__(256) void prep_x_kernel(const float* __restrict__ x,
                                                     f16* __restrict__ xpk) {
  int idx = blockIdx.x * 256 + threadIdx.x;  // over T*B*(D/8)
  int seg = idx & 63;
  int b   = (idx >> 6) & 63;
  int t   = idx >> 12;
  float4 u = *(const float4*)(x + ((size_t)b * TT + t) * DD + seg * 8);
  float4 v = *(const float4*)(x + ((size_t)b * TT + t) * DD + seg * 8 + 4);
  f16x8 o = {(f16)u.x, (f16)u.y, (f16)u.z, (f16)u.w,
             (f16)v.x, (f16)v.y, (f16)v.z, (f16)v.w};
  int ch = seg >> 2, kgrp = seg & 3;
  *(f16x8*)(xpk + ((size_t)((t * 4 + (b >> 4)) * 16 + ch) * 64 +
                   kgrp * 16 + (b & 15)) * 8) = o;
}

// ---- persistent 2-layer LSTM: asymmetric sync-shadowed slack (R20) ----
// Final state = R20, the session's verified best (1297.7 us):
//  * dataflow sync (no global barrier): per-block producer flags ->
//    per-layer aggregator -> 32 replicated epoch lines; consumers poll one
//    replica each with s_sleep backoff (fan-in discipline: R8/R15 lessons).
//  * aggregator polls + publishes FIRST, then computes (R12/R16/R20 lesson:
//    agg's compute must not gate the global critical chain).
//  * non-agg blocks consume slack (L0: x[t]; L1: h0[u]) DURING the epoch
//    wait; critical (recurrent) matmul after the gate with asm-forced
//    16-deep load pipeline + progressive counted vmcnt.
//  * fragment-packed h rings (RING=64): coalesced 1KB/instr A-loads, sc1
//    write-through stores; ring reuse distance guards staleness (no cache
//    invalidates anywhere).
__global__ __launch_bounds__(512, 2) void lstm_persistent(
    const f16* __restrict__ xpk,
    const float* __restrict__ Wih0, const float* __restrict__ Whh0,
    const float* __restrict__ bih0, const float* __restrict__ bhh0,
    const float* __restrict__ Wih1, const float* __restrict__ Whh1,
    const float* __restrict__ bih1, const float* __restrict__ bhh1,
    f16* __restrict__ h0ring, f16* __restrict__ h1ring, int* __restrict__ bar) {
  extern __shared__ f16 lds[];
  const int bid  = blockIdx.x;
  const bool IS1 = (bid >= L0B);
  const int j0   = (IS1 ? bid - L0B : bid) * COLS;
  const int tid  = threadIdx.x;
  const int wv   = tid >> 6;
  const int lane = tid & 63;
  const int kh   = wv >> 2;     // K-half
  const int bt   = wv & 3;      // batch tile (16 rows)
  const int col  = lane & 15;
  const int kgrp = lane >> 4;
  const int jc   = col & 7;
  const int ch0  = j0 >> 5;
  const int kg0  = (j0 >> 3) & 3;

  const int CHK = IS1 ? CHK1 : CHK0;
  const int TS  = IS1 ? TS1 : TS0;
  const int DIN = IS1 ? HH : DD;
  f16* Wpk    = lds;
  float* pbuf = (float*)(lds + 2 * TS1);     // [4][64] stride 9 (conflict-free)
  f16* hbuf   = (f16*)(pbuf + 4 * 64 * 9);   // [64][8]

  // ---- prologue: pack weights into MFMA-fragment order (fp32 -> fp16) ----
  {
    const float* Wi = IS1 ? Wih1 : Wih0;
    const float* Wh = IS1 ? Whh1 : Whh0;
    const int grow = (kh * 2 + (col >> 3)) * HH + j0 + jc;
    const float* rowi = Wi + (size_t)grow * DIN;
    const float* rowh = Wh + (size_t)grow * HH;
    for (int ck = bt; ck < CHK; ck += 4) {
      int k = ck * 32 + kgrp * 8;
      const float* src = (k < DIN) ? (rowi + k) : (rowh + (k - DIN));
      float4 u = *(const float4*)src;
      float4 v = *(const float4*)(src + 4);
      f16x8 w = {(f16)u.x, (f16)u.y, (f16)u.z, (f16)u.w,
                 (f16)v.x, (f16)v.y, (f16)v.z, (f16)v.w};
      *(f16x8*)(Wpk + (size_t)kh * TS + (size_t)ck * 512 + lane * 8) = w;
    }
  }
  const float* bi = IS1 ? bih1 : bih0;
  const float* bh = IS1 ? bhh1 : bhh0;
  const int g0 = (col < 8) ? 0 : 1;
  const int g1 = (col < 8) ? 2 : 3;
  const float bias0 = bi[g0 * HH + j0 + jc] + bh[g0 * HH + j0 + jc];
  const float bias1 = bi[g1 * HH + j0 + jc] + bh[g1 * HH + j0 + jc];
  __syncthreads();

  float creg[4] = {0.f, 0.f, 0.f, 0.f};
  int* flag0 = bar;
  int* flag1 = bar + L0B * 32;
  int* ep0   = bar + 2 * L0B * 32;
  int* ep1   = ep0 + GRP * 32;
  const int myrep = (IS1 ? bid - L0B : bid) & (GRP - 1);
  const f16* w0 = Wpk + lane * 8;
  const f16* w1 = Wpk + (size_t)TS + lane * 8;

  auto cellstore = [&](f32x4 aA0, f32x4 aA1, f32x4 aB0, f32x4 aB1, f16* hw) {
    if (kh == 1) {
      #pragma unroll
      for (int r = 0; r < 4; ++r) {
        pbuf[((size_t)bt * 64 + lane) * 9 + r]     = aA0[r] + aA1[r];
        pbuf[((size_t)bt * 64 + lane) * 9 + 4 + r] = aB0[r] + aB1[r];
      }
    }
    __syncthreads();
    if (kh == 0) {
      #pragma unroll
      for (int r = 0; r < 4; ++r) {
        float pv0 = aA0[r] + aA1[r] + pbuf[((size_t)bt * 64 + lane) * 9 + r] + bias0;
        float pv1 = aB0[r] + aB1[r] + pbuf[((size_t)bt * 64 + lane) * 9 + 4 + r] + bias1;
        float q0 = __shfl_xor(pv0, 8);
        float q1 = __shfl_xor(pv1, 8);
        if (col < 8) {
          float ig = FSIG(pv0);
          float fg = FSIG(q0);
          float gg = FTANH(pv1);
          float og = FSIG(q1);
          float cc = fg * creg[r] + ig * gg;
          creg[r] = cc;
          hbuf[((size_t)bt * 16 + kgrp * 4 + r) * 8 + jc] = (f16)(og * FTANH(cc));
        }
      }
      if (lane < 16) {
        f16x8 hv = *(const f16x8*)(hbuf + ((size_t)bt * 16 + lane) * 8);
        f16* dst = hw + ((size_t)(bt * 32 + ch0) * 64 + kg0 * 16 + lane) * 8;
        i32x4 hvi;
        __builtin_memcpy(&hvi, &hv, 16);
        asm volatile("global_store_dwordx4 %0, %1, off sc1"
                     :: "v"(dst), "v"(hvi) : "memory");
      }
    }
  };

  if (!IS1) {
    // ================= layer 0 =================
    const bool AGG = (bid == 0);
    i32x4 afs[8];   // x slack: 8 chunks per kh half (prefetched)
    i32x4 afc[16];  // critical h0 half
    // prologue: x[0] slack in flight (no dependency)
    glP<8>(afs, xpk + (size_t)(0 * 4 + bt) * 16 * 512 +
                (size_t)kh * 8 * 512 + lane * 8);
    for (int t = 0; t < TT; ++t) {
      f32x4 aA0 = {0.f,0.f,0.f,0.f}, aA1 = {0.f,0.f,0.f,0.f};
      f32x4 aB0 = {0.f,0.f,0.f,0.f}, aB1 = {0.f,0.f,0.f,0.f};
      if (AGG) {
        // --- agg: poll + publish FIRST, slack after (off critical chain) ---
        if (tid < L0B)
          while (__hip_atomic_load(flag0 + tid * 32, __ATOMIC_RELAXED, ALOAD) < t)
            __builtin_amdgcn_s_sleep(1);
        if (tid == 256) {   // ring slot free of L1 readers
          while (__hip_atomic_load(ep1 + myrep * 32, __ATOMIC_RELAXED, ALOAD) < t - (RING - 1))
            __builtin_amdgcn_s_sleep(EPSLP);
        }
        __syncthreads();
        if (tid < GRP)
          __hip_atomic_store(ep0 + tid * 32, t, __ATOMIC_RELAXED, ALOAD);
        if (kh == 0) mf2<8, 0, 0>(afs, w0, w1, aA0, aA1, aB0, aB1);
        else         mf2<8, 0, 8>(afs, w0, w1, aA0, aA1, aB0, aB1);
      } else {
        // --- non-agg: slack consume overlaps the epoch wait ---
        if (kh == 0) mf2<8, 0, 0>(afs, w0, w1, aA0, aA1, aB0, aB1);
        else         mf2<8, 0, 8>(afs, w0, w1, aA0, aA1, aB0, aB1);
        if (tid == 0) {
          while (__hip_atomic_load(ep0 + myrep * 32, __ATOMIC_RELAXED, ALOAD) < t)
            __builtin_amdgcn_s_sleep(EPSLP);
        }
        if (tid == 256) {   // ring slot free of L1 readers
          while (__hip_atomic_load(ep1 + myrep * 32, __ATOMIC_RELAXED, ALOAD) < t - (RING - 1))
            __builtin_amdgcn_s_sleep(EPSLP);
        }
        __syncthreads();
      }
      // --- critical: h0[t-1], 16 chunks per wave ---
      const f16* hp = h0ring + (size_t)((t - 1) & (RING - 1)) * HSZ +
                      (size_t)(bt * 32 + kh * 16) * 512 + lane * 8;
      glP<16>(afc, hp);
      if (kh == 0) mf2<16, 0, 16>(afc, w0, w1, aA0, aA1, aB0, aB1);
      else         mf2<16, 0, 32>(afc, w0, w1, aA0, aA1, aB0, aB1);
      cellstore(aA0, aA1, aB0, aB1, h0ring + (size_t)(t & (RING - 1)) * HSZ);
      asm volatile("s_waitcnt vmcnt(0)" ::: "memory");
      __syncthreads();
      if (tid == 0)
        __hip_atomic_store(flag0 + bid * 32, t + 1, __ATOMIC_RELAXED, ALOAD);
      // --- prefetch x[t+1] slack (static, no gate) flies across sync ---
      if (t + 1 < TT)
        glP<8>(afs, xpk + (size_t)((t + 1) * 4 + bt) * 16 * 512 +
                    (size_t)kh * 8 * 512 + lane * 8);
    }
    if (AGG) {   // final epoch pass for L1's last prefetch gate
      if (tid < L0B)
        while (__hip_atomic_load(flag0 + tid * 32, __ATOMIC_RELAXED, ALOAD) < TT)
          __builtin_amdgcn_s_sleep(1);
      __syncthreads();
      if (tid < GRP)
        __hip_atomic_store(ep0 + tid * 32, TT, __ATOMIC_RELAXED, ALOAD);
    }
  } else {
    // ================= layer 1 =================
    const bool AGG = (bid == L0B);
    i32x4 afs[16];  // h0 slack: 16 chunks per kh half (prefetched)
    i32x4 afc[16];  // critical h1 half
    {  // prologue: gate h0[0] ready, then slack loads in flight (both kh)
      if (tid == 0)
        while (__hip_atomic_load(ep0 + myrep * 32, __ATOMIC_RELAXED, ALOAD) < 1)
          __builtin_amdgcn_s_sleep(EPSLP);
      __syncthreads();
      glP<16>(afs, h0ring + (size_t)0 * HSZ +
                   (size_t)(bt * 32 + kh * 16) * 512 + lane * 8);
    }
    for (int u = 0; u < TT; ++u) {
      f32x4 aA0 = {0.f,0.f,0.f,0.f}, aA1 = {0.f,0.f,0.f,0.f};
      f32x4 aB0 = {0.f,0.f,0.f,0.f}, aB1 = {0.f,0.f,0.f,0.f};
      if (AGG) {
        // --- agg: poll + publish FIRST, slack after (off critical chain) ---
        if (tid < L0B)
          while (__hip_atomic_load(flag1 + tid * 32, __ATOMIC_RELAXED, ALOAD) < u)
            __builtin_amdgcn_s_sleep(1);
        __syncthreads();
        if (tid < GRP)
          __hip_atomic_store(ep1 + tid * 32, u, __ATOMIC_RELAXED, ALOAD);
        if (kh == 0) mf2<16, 0, 0>(afs, w0, w1, aA0, aA1, aB0, aB1);
        else         mf2<16, 0, 16>(afs, w0, w1, aA0, aA1, aB0, aB1);
      } else {
        // --- non-agg: slack consume overlaps the epoch wait ---
        if (kh == 0) mf2<16, 0, 0>(afs, w0, w1, aA0, aA1, aB0, aB1);
        else         mf2<16, 0, 16>(afs, w0, w1, aA0, aA1, aB0, aB1);
        if (tid == 0) {
          while (__hip_atomic_load(ep1 + myrep * 32, __ATOMIC_RELAXED, ALOAD) < u)
            __builtin_amdgcn_s_sleep(EPSLP);
        }
        __syncthreads();
      }
      // --- critical: h1[u-1], 16 chunks per wave ---
      const f16* h1p = h1ring + (size_t)((u - 1) & (RING - 1)) * HSZ +
                       (size_t)(bt * 32 + kh * 16) * 512 + lane * 8;
      glP<16>(afc, h1p);
      if (kh == 0) mf2<16, 0, 32>(afc, w0, w1, aA0, aA1, aB0, aB1);
      else         mf2<16, 0, 48>(afc, w0, w1, aA0, aA1, aB0, aB1);
      cellstore(aA0, aA1, aB0, aB1, h1ring + (size_t)(u & (RING - 1)) * HSZ);
      asm volatile("s_waitcnt vmcnt(0)" ::: "memory");
      __syncthreads();
      if (tid == 0)
        __hip_atomic_store(flag1 + (bid - L0B) * 32, u + 1, __ATOMIC_RELAXED, ALOAD);
      // --- gated slack prefetch h0[u+1] (both kh halves) ---
      if (u + 1 < TT) {
        if (tid == 256)
          while (__hip_atomic_load(ep0 + myrep * 32, __ATOMIC_RELAXED, ALOAD) < u + 2)
            __builtin_amdgcn_s_sleep(EPSLP);
        __syncthreads();
        glP<16>(afs, h0ring + (size_t)((u + 1) & (RING - 1)) * HSZ +
                     (size_t)(bt * 32 + kh * 16) * 512 + lane * 8);
      }
    }
  }
}

// ---- FC over packed finals ----
__global__ __launch_bounds__(256) void fc_kernel(const f16* __restrict__ h0f,
                                                 const f16* __restrict__ h1f,
                                                 const float* __restrict__ Wfc,
                                                 const float* __restrict__ bfc,
                                                 float* __restrict__ out) {
  __shared__ f16 hl[64][264];
  __shared__ float Wl[4][260];
  const int tid = threadIdx.x;
  const int cl0 = blockIdx.x * 4;
  const int b   = tid >> 2;
  const int cq  = tid & 3;
  float a = 0.f;
  for (int k0 = 0; k0 < 2 * HH; k0 += 256) {
    #pragma unroll
    for (int i = 0; i < 8; i++) {
      int v   = tid + i * 256;
      int row = v >> 5;
      int kk  = (v & 31) * 8;
      int kg  = k0 + kk;
      int kg2 = (kg < HH) ? kg : kg - HH;
      const f16* bse = (kg < HH) ? h0f : h1f;
      const f16* src = bse + ((size_t)((row >> 4) * 32 + (kg2 >> 5)) * 64 +
                              ((kg2 >> 3) & 3) * 16 + (row & 15)) * 8;
      *(f16x8*)(&hl[row][kk]) = *(const f16x8*)src;
    }
    {
      int row = tid >> 6;
      int kk  = (tid & 63) * 4;
      *(float4*)(&Wl[row][kk]) = *(const float4*)(Wfc + (size_t)(cl0 + row) * (2 * HH) + k0 + kk);
    }
    __syncthreads();
    #pragma unroll 8
    for (int k = 0; k < 256; k++) a += (float)hl[b][k] * Wl[cq][k];
    __syncthreads();
  }
  out[(size_t)b * NCLS + cl0 + cq] = a + bfc[cl0 + cq];
}

extern "C" void kernel_launch(void* const* d_in, const int* in_sizes, int n_in,
                              void* d_out, int out_size, void* d_ws, size_t ws_size,
                              hipStream_t stream) {
  const float* x    = (const float*)d_in[0];
  const float* Wih0 = (const float*)d_in[1];
  const float* Whh0 = (const float*)d_in[2];
  const float* bih0 = (const float*)d_in[3];
  const float* bhh0 = (const float*)d_in[4];
  const float* Wih1 = (const float*)d_in[5];
  const float* Whh1 = (const float*)d_in[6];
  const float* bih1 = (const float*)d_in[7];
  const float* bhh1 = (const float*)d_in[8];
  const float* Wfc  = (const float*)d_in[9];
  const float* bfc  = (const float*)d_in[10];
  float* out = (float*)d_out;

  char* p = (char*)d_ws;
  auto alloc = [&](size_t bytes) {
    char* r = p;
    p += (bytes + 255) & ~(size_t)255;
    return r;
  };
  f16* xpk    = (f16*)alloc((size_t)BB * TT * DD * 2);
  f16* h0ring = (f16*)alloc((size_t)RING * HSZ * 2);
  f16* h1ring = (f16*)alloc((size_t)RING * HSZ * 2);
  int* bar    = (int*)alloc((size_t)BARWORDS * 4);

  if ((size_t)(p - (char*)d_ws) > ws_size) return;  // ws too small: bail cleanly

  (void)hipMemsetAsync(bar, 0, (size_t)BARWORDS * 4, stream);
  // slot RING-1 = t=-1 zeros for both rings
  (void)hipMemsetAsync(h0ring + (size_t)(RING - 1) * HSZ, 0, (size_t)HSZ * 2, stream);
  (void)hipMemsetAsync(h1ring + (size_t)(RING - 1) * HSZ, 0, (size_t)HSZ * 2, stream);

  prep_x_kernel<<<dim3(TT * BB * (DD / 8) / 256), dim3(256), 0, stream>>>(x, xpk);

  (void)hipFuncSetAttribute((const void*)lstm_persistent,
                            hipFuncAttributeMaxDynamicSharedMemorySize, DYNLDS);
  lstm_persistent<<<dim3(NB), dim3(512), DYNLDS, stream>>>(
      xpk, Wih0, Whh0, bih0, bhh0, Wih1, Whh1, bih1, bhh1, h0ring, h1ring, bar);

  // h0[255] -> slot 255&63 = 63; h1[255] -> slot 63
  fc_kernel<<<dim3(NCLS / 4), dim3(256), 0, stream>>>(
      h0ring + (size_t)(RING - 1) * HSZ, h1ring + (size_t)(RING - 1) * HSZ,
      Wfc, bfc, out);
}